// Round 9
// baseline (349.784 us; speedup 1.0000x reference)
//
#include <hip/hip_runtime.h>
#include <hip/hip_bf16.h>

#define N_NODES 40000
#define N_EDGES 640000
#define IN_DIM 128
#define HIDDEN 128
#define OUT_DIM 64
#define N_GRAPHS 64
#define CAP 64   // bucket capacity per node (Poisson(16); P(max>=64) ~ 4e-15)

// RNE round fp32->bf16, pack two into a uint (a -> low16, b -> high16)
__device__ inline unsigned int pack_bf2(float a, float b) {
  unsigned int ua = __float_as_uint(a);
  ua = ua + 0x7fffu + ((ua >> 16) & 1u);
  unsigned int ub = __float_as_uint(b);
  ub = ub + 0x7fffu + ((ub >> 16) & 1u);
  return (ua >> 16) | (ub & 0xffff0000u);
}

// ---------------------------------------------------------------------------
// Single-pass bucket scatter: cnt[d]++ and record src in d's bucket (ushort).
// ---------------------------------------------------------------------------
__global__ __launch_bounds__(256) void scatter_bucket_kernel(
    const int* __restrict__ src, const int* __restrict__ dst,
    int* __restrict__ cnt, unsigned short* __restrict__ bucket) {
  int e = blockIdx.x * 256 + threadIdx.x;
  if (e >= N_EDGES) return;
  int d = dst[e];
  int s = src[e];
  int p = atomicAdd(&cnt[d], 1);
  if (p < CAP) bucket[(size_t)d * CAP + p] = (unsigned short)s;
}

// dinv[n] = rsqrt(cnt[n] + 1)   (self-loop)
__global__ __launch_bounds__(256) void dinv_kernel(
    const int* __restrict__ cnt, float* __restrict__ dinv) {
  int n = blockIdx.x * 256 + threadIdx.x;
  if (n < N_NODES) dinv[n] = rsqrtf((float)cnt[n] + 1.0f);
}

// ---------------------------------------------------------------------------
// Finalize: one wave per node. Re-pack bucket entry -> uint:
//   (bf16(dinv[src]) << 16) | src
// ---------------------------------------------------------------------------
__global__ __launch_bounds__(256) void finalize_kernel(
    const int* __restrict__ cnt, const unsigned short* __restrict__ bucket,
    const float* __restrict__ dinv, unsigned int* __restrict__ bucket2) {
  int wave = threadIdx.x >> 6;
  int lane = threadIdx.x & 63;
  int n = blockIdx.x * 4 + wave;
  int ecnt = min(cnt[n], CAP);
  unsigned int v = 0;
  if (lane < ecnt) {
    int s = bucket[(size_t)n * CAP + lane];
    unsigned int d = __float_as_uint(dinv[s]);
    d = d + 0x7fffu + ((d >> 16) & 1u);          // RNE to bf16
    v = (d & 0xffff0000u) | (unsigned int)s;
  }
  bucket2[(size_t)n * CAP + lane] = v;
}

// ---------------------------------------------------------------------------
// fp32-input GEMM, bf16 output: C[M,128] = A[M,128] @ W[128,128].
// ---------------------------------------------------------------------------
__global__ __launch_bounds__(256) void gemm_f32_kernel(
    const float* __restrict__ A, const float* __restrict__ W,
    unsigned int* __restrict__ C) {  // C: bf16 pairs, row stride 64 uints
  __shared__ float As[8][65];
  __shared__ float Bs[8][128];
  int t = threadIdx.x;
  int tx = t & 15;
  int ty = t >> 4;
  int rowBase = blockIdx.x * 64;

  float acc[4][8];
#pragma unroll
  for (int i = 0; i < 4; ++i)
#pragma unroll
    for (int j = 0; j < 8; ++j) acc[i][j] = 0.0f;

  int arow = t >> 2;          // 0..63
  int akk = (t & 3) * 2;      // 0,2,4,6
  int bkk = t >> 5;           // 0..7
  int bcol = (t & 31) * 4;    // 0..124

  const float* Aptr = A + (size_t)(rowBase + arow) * 128 + akk;

  for (int kb = 0; kb < 128; kb += 8) {
    float2 av = *(const float2*)(Aptr + kb);
    float4 bv = *(const float4*)(W + (kb + bkk) * 128 + bcol);
    As[akk][arow] = av.x;
    As[akk + 1][arow] = av.y;
    *(float4*)&Bs[bkk][bcol] = bv;
    __syncthreads();
#pragma unroll
    for (int kk = 0; kk < 8; ++kk) {
      float a[4], b[8];
#pragma unroll
      for (int i = 0; i < 4; ++i) a[i] = As[kk][ty * 4 + i];
#pragma unroll
      for (int j = 0; j < 8; ++j) b[j] = Bs[kk][tx * 8 + j];
#pragma unroll
      for (int i = 0; i < 4; ++i)
#pragma unroll
        for (int j = 0; j < 8; ++j) acc[i][j] = fmaf(a[i], b[j], acc[i][j]);
    }
    __syncthreads();
  }

#pragma unroll
  for (int i = 0; i < 4; ++i) {
    unsigned int* cp = C + (size_t)(rowBase + ty * 4 + i) * 64 + tx * 4;
    uint4 v;
    v.x = pack_bf2(acc[i][0], acc[i][1]);
    v.y = pack_bf2(acc[i][2], acc[i][3]);
    v.z = pack_bf2(acc[i][4], acc[i][5]);
    v.w = pack_bf2(acc[i][6], acc[i][7]);
    *(uint4*)cp = v;
  }
}

// ---------------------------------------------------------------------------
// bf16-input GEMM (A = packed bf16 pairs, nontemporal read), bf16 output.
// ---------------------------------------------------------------------------
__global__ __launch_bounds__(256) void gemm_bf16_kernel(
    const unsigned int* __restrict__ A, const float* __restrict__ W,
    unsigned int* __restrict__ C) {
  __shared__ float As[8][65];
  __shared__ float Bs[8][128];
  int t = threadIdx.x;
  int tx = t & 15;
  int ty = t >> 4;
  int rowBase = blockIdx.x * 64;

  float acc[4][8];
#pragma unroll
  for (int i = 0; i < 4; ++i)
#pragma unroll
    for (int j = 0; j < 8; ++j) acc[i][j] = 0.0f;

  int arow = t >> 2;          // 0..63
  int akk = (t & 3) * 2;      // 0,2,4,6
  int bkk = t >> 5;           // 0..7
  int bcol = (t & 31) * 4;    // 0..124

  const unsigned int* Aptr = A + (size_t)(rowBase + arow) * 64 + (akk >> 1);

  for (int kb = 0; kb < 128; kb += 8) {
    unsigned int av = __builtin_nontemporal_load(Aptr + (kb >> 1));
    float4 bv = *(const float4*)(W + (kb + bkk) * 128 + bcol);
    As[akk][arow] = __uint_as_float(av << 16);
    As[akk + 1][arow] = __uint_as_float(av & 0xffff0000u);
    *(float4*)&Bs[bkk][bcol] = bv;
    __syncthreads();
#pragma unroll
    for (int kk = 0; kk < 8; ++kk) {
      float a[4], b[8];
#pragma unroll
      for (int i = 0; i < 4; ++i) a[i] = As[kk][ty * 4 + i];
#pragma unroll
      for (int j = 0; j < 8; ++j) b[j] = Bs[kk][tx * 8 + j];
#pragma unroll
      for (int i = 0; i < 4; ++i)
#pragma unroll
        for (int j = 0; j < 8; ++j) acc[i][j] = fmaf(a[i], b[j], acc[i][j]);
    }
    __syncthreads();
  }

#pragma unroll
  for (int i = 0; i < 4; ++i) {
    unsigned int* cp = C + (size_t)(rowBase + ty * 4 + i) * 64 + tx * 4;
    uint4 v;
    v.x = pack_bf2(acc[i][0], acc[i][1]);
    v.y = pack_bf2(acc[i][2], acc[i][3]);
    v.z = pack_bf2(acc[i][4], acc[i][5]);
    v.w = pack_bf2(acc[i][6], acc[i][7]);
    *(uint4*)cp = v;
  }
}

// ---------------------------------------------------------------------------
// Aggregation over bf16 h. One wave per node; lane owns channels 2l,2l+1.
// EXACT byte count: unroll-16 blocks with wave-uniform guards; guarded-off
// loads issue no memory traffic. Two-phase (guarded load array -> fma) keeps
// 16 independent gathers in flight. readlane (not shfl) guarantees the SGPR
// broadcast path - no LDS pipe in the loop.
// pool==0: write bf16 packed, NONTEMPORAL (don't evict h from L2).
// pool==1: atomicAdd into per-graph sums.
// ---------------------------------------------------------------------------
__global__ __launch_bounds__(256) void agg_relu_kernel(
    const unsigned int* __restrict__ h, const int* __restrict__ cnt,
    const unsigned int* __restrict__ bucket2,
    const float* __restrict__ dinv, const float* __restrict__ bias,
    unsigned int* __restrict__ outb, const int* __restrict__ batch,
    float* __restrict__ sums, int pool) {
  int wave = threadIdx.x >> 6;
  int lane = threadIdx.x & 63;
  int n = blockIdx.x * 4 + wave;

  unsigned int ev =
      __builtin_nontemporal_load(&bucket2[(size_t)n * CAP + lane]);
  int ecnt = min(cnt[n], CAP);
  float di = dinv[n];

  float accx = 0.0f, accy = 0.0f;
  for (int eb = 0; eb < ecnt; eb += 16) {
    unsigned int hv[16];
    float nmv[16];
#pragma unroll
    for (int i = 0; i < 16; ++i) {
      hv[i] = 0u;
      nmv[i] = 0.0f;
      int e = eb + i;
      if (e < ecnt) {                                  // wave-uniform guard
        unsigned int edge = __builtin_amdgcn_readlane(ev, e);
        int s = (int)(edge & 0xffffu);
        nmv[i] = __uint_as_float(edge & 0xffff0000u) * di;
        hv[i] = h[(size_t)s * 64 + lane];
      }
    }
#pragma unroll
    for (int i = 0; i < 16; ++i) {
      accx = fmaf(__uint_as_float(hv[i] << 16), nmv[i], accx);
      accy = fmaf(__uint_as_float(hv[i] & 0xffff0000u), nmv[i], accy);
    }
  }

  float sl = di * di;
  unsigned int hsv = h[(size_t)n * 64 + lane];
  float hsx = __uint_as_float(hsv << 16);
  float hsy = __uint_as_float(hsv & 0xffff0000u);
  float2 bv = ((const float2*)bias)[lane];
  float vx = fmaxf(fmaf(sl, hsx, accx) + bv.x, 0.0f);
  float vy = fmaxf(fmaf(sl, hsy, accy) + bv.y, 0.0f);

  if (!pool) {
    unsigned int o = pack_bf2(vx, vy);
    __builtin_nontemporal_store(o, &outb[(size_t)n * 64 + lane]);
  } else {
    int g = batch[n];
    atomicAdd(&sums[g * 128 + 2 * lane], vx);
    atomicAdd(&sums[g * 128 + 2 * lane + 1], vy);
  }
}

// ---------------------------------------------------------------------------
// Head: per-graph count via binary search on sorted batch (folded in),
// g = sums/cnt; out = normalize(g @ Wl + bl). 1 wave per graph.
// ---------------------------------------------------------------------------
__global__ __launch_bounds__(64) void head_kernel(
    const int* __restrict__ batch, const float* __restrict__ sums,
    const float* __restrict__ Wl, const float* __restrict__ bl,
    float* __restrict__ out) {
  int g = blockIdx.x;
  int j = threadIdx.x;
  __shared__ float gv[128];
  __shared__ int bnd[2];
  if (j < 2) {
    int v = g + j;
    int lo = 0, hi = N_NODES;
    while (lo < hi) {
      int m = (lo + hi) >> 1;
      if (batch[m] < v) lo = m + 1; else hi = m;
    }
    bnd[j] = lo;
  }
  __syncthreads();
  float c = fmaxf((float)(bnd[1] - bnd[0]), 1.0f);
  float inv = 1.0f / c;
  gv[j] = sums[g * 128 + j] * inv;
  gv[j + 64] = sums[g * 128 + 64 + j] * inv;
  __syncthreads();
  float acc = bl[j];
#pragma unroll 8
  for (int k = 0; k < 128; ++k) acc = fmaf(gv[k], Wl[k * 64 + j], acc);
  float ss = acc * acc;
#pragma unroll
  for (int d = 32; d > 0; d >>= 1) ss += __shfl_xor(ss, d);
  float nrm = sqrtf(ss);
  out[g * 64 + j] = acc / fmaxf(nrm, 1e-12f);
}

// ---------------------------------------------------------------------------
extern "C" void kernel_launch(void* const* d_in, const int* in_sizes, int n_in,
                              void* d_out, int out_size, void* d_ws, size_t ws_size,
                              hipStream_t stream) {
  const float* x  = (const float*)d_in[0];
  const float* W1 = (const float*)d_in[1];
  const float* b1 = (const float*)d_in[2];
  const float* W2 = (const float*)d_in[3];
  const float* b2 = (const float*)d_in[4];
  const float* Wl = (const float*)d_in[5];
  const float* bl = (const float*)d_in[6];
  const int* edge_index = (const int*)d_in[7];   // [2, E] int32
  const int* batch = (const int*)d_in[8];
  float* out = (float*)d_out;

  const int* esrc_in = edge_index;
  const int* edst_in = edge_index + N_EDGES;

  // workspace carve-up (~36.2 MB)
  char* p = (char*)d_ws;
  unsigned int* bufA = (unsigned int*)p;                      // bf16 h (pairs)
  p += (size_t)N_NODES * 64 * 4;                              // 10.24 MB
  unsigned int* bufB = (unsigned int*)p;                      // bf16 relu out
  p += (size_t)N_NODES * 64 * 4;                              // 10.24 MB
  int* cnt    = (int*)p;    p += (size_t)N_NODES * 4;         // 160 KB
  float* sums = (float*)p;  p += (size_t)N_GRAPHS * 128 * 4;  // 32 KB
  float* dinv = (float*)p;  p += (size_t)N_NODES * 4;         // 160 KB
  unsigned short* bucket = (unsigned short*)p;
  p += (size_t)N_NODES * CAP * 2;                              // 5.12 MB
  unsigned int* bucket2 = (unsigned int*)p;
  p += (size_t)N_NODES * CAP * 4;                              // 10.24 MB

  // zero cnt + sums in one contiguous memset (adjacent)
  hipMemsetAsync(cnt, 0, (size_t)N_NODES * 4 + (size_t)N_GRAPHS * 128 * 4,
                 stream);

  int ceilN = (N_NODES + 255) / 256;   // 157
  int ceilE = (N_EDGES + 255) / 256;   // 2500

  scatter_bucket_kernel<<<ceilE, 256, 0, stream>>>(esrc_in, edst_in, cnt, bucket);
  dinv_kernel<<<ceilN, 256, 0, stream>>>(cnt, dinv);
  finalize_kernel<<<N_NODES / 4, 256, 0, stream>>>(cnt, bucket, dinv, bucket2);

  // layer 1: h = bf16(x @ W1) ; agg+bias+relu -> bufB (bf16, nontemporal)
  gemm_f32_kernel<<<N_NODES / 64, 256, 0, stream>>>(x, W1, bufA);
  agg_relu_kernel<<<N_NODES / 4, 256, 0, stream>>>(
      bufA, cnt, bucket2, dinv, b1, bufB, batch, sums, 0);

  // layer 2: h = bf16(bufB @ W2) ; agg+bias+relu fused with mean-pool accum
  gemm_bf16_kernel<<<N_NODES / 64, 256, 0, stream>>>(bufB, W2, bufA);
  agg_relu_kernel<<<N_NODES / 4, 256, 0, stream>>>(
      bufA, cnt, bucket2, dinv, b2, nullptr, batch, sums, 1);

  // head: count via binary search, mean, linear, L2 normalize
  head_kernel<<<N_GRAPHS, 64, 0, stream>>>(batch, sums, Wl, bl, out);
}

// Round 14
// 321.696 us; speedup vs baseline: 1.0873x; 1.0873x over previous
//
#include <hip/hip_runtime.h>
#include <hip/hip_bf16.h>

#define N_NODES 40000
#define N_EDGES 640000
#define IN_DIM 128
#define HIDDEN 128
#define OUT_DIM 64
#define N_GRAPHS 64
#define CAP 64   // bucket capacity per node (Poisson(16); P(max>=64) ~ 4e-15)

// RNE round fp32->bf16, pack two into a uint (a -> low16, b -> high16)
__device__ inline unsigned int pack_bf2(float a, float b) {
  unsigned int ua = __float_as_uint(a);
  ua = ua + 0x7fffu + ((ua >> 16) & 1u);
  unsigned int ub = __float_as_uint(b);
  ub = ub + 0x7fffu + ((ub >> 16) & 1u);
  return (ua >> 16) | (ub & 0xffff0000u);
}

// ---------------------------------------------------------------------------
// Single-pass bucket scatter: cnt[d]++ and record src in d's bucket (ushort).
// ---------------------------------------------------------------------------
__global__ __launch_bounds__(256) void scatter_bucket_kernel(
    const int* __restrict__ src, const int* __restrict__ dst,
    int* __restrict__ cnt, unsigned short* __restrict__ bucket) {
  int e = blockIdx.x * 256 + threadIdx.x;
  if (e >= N_EDGES) return;
  int d = dst[e];
  int s = src[e];
  int p = atomicAdd(&cnt[d], 1);
  if (p < CAP) bucket[(size_t)d * CAP + p] = (unsigned short)s;
}

// dinv[n] = rsqrt(cnt[n] + 1)   (self-loop)
__global__ __launch_bounds__(256) void dinv_kernel(
    const int* __restrict__ cnt, float* __restrict__ dinv) {
  int n = blockIdx.x * 256 + threadIdx.x;
  if (n < N_NODES) dinv[n] = rsqrtf((float)cnt[n] + 1.0f);
}

// ---------------------------------------------------------------------------
// Finalize: one wave per node. Re-pack bucket entry -> uint:
//   (bf16(dinv[src]) << 16) | src
// ---------------------------------------------------------------------------
__global__ __launch_bounds__(256) void finalize_kernel(
    const int* __restrict__ cnt, const unsigned short* __restrict__ bucket,
    const float* __restrict__ dinv, unsigned int* __restrict__ bucket2) {
  int wave = threadIdx.x >> 6;
  int lane = threadIdx.x & 63;
  int n = blockIdx.x * 4 + wave;
  int ecnt = min(cnt[n], CAP);
  unsigned int v = 0;
  if (lane < ecnt) {
    int s = bucket[(size_t)n * CAP + lane];
    unsigned int d = __float_as_uint(dinv[s]);
    d = d + 0x7fffu + ((d >> 16) & 1u);          // RNE to bf16
    v = (d & 0xffff0000u) | (unsigned int)s;
  }
  bucket2[(size_t)n * CAP + lane] = v;
}

// ---------------------------------------------------------------------------
// fp32-input GEMM, bf16 output: C[M,128] = A[M,128] @ W[128,128].
// ---------------------------------------------------------------------------
__global__ __launch_bounds__(256) void gemm_f32_kernel(
    const float* __restrict__ A, const float* __restrict__ W,
    unsigned int* __restrict__ C) {  // C: bf16 pairs, row stride 64 uints
  __shared__ float As[8][65];
  __shared__ float Bs[8][128];
  int t = threadIdx.x;
  int tx = t & 15;
  int ty = t >> 4;
  int rowBase = blockIdx.x * 64;

  float acc[4][8];
#pragma unroll
  for (int i = 0; i < 4; ++i)
#pragma unroll
    for (int j = 0; j < 8; ++j) acc[i][j] = 0.0f;

  int arow = t >> 2;          // 0..63
  int akk = (t & 3) * 2;      // 0,2,4,6
  int bkk = t >> 5;           // 0..7
  int bcol = (t & 31) * 4;    // 0..124

  const float* Aptr = A + (size_t)(rowBase + arow) * 128 + akk;

  for (int kb = 0; kb < 128; kb += 8) {
    float2 av = *(const float2*)(Aptr + kb);
    float4 bv = *(const float4*)(W + (kb + bkk) * 128 + bcol);
    As[akk][arow] = av.x;
    As[akk + 1][arow] = av.y;
    *(float4*)&Bs[bkk][bcol] = bv;
    __syncthreads();
#pragma unroll
    for (int kk = 0; kk < 8; ++kk) {
      float a[4], b[8];
#pragma unroll
      for (int i = 0; i < 4; ++i) a[i] = As[kk][ty * 4 + i];
#pragma unroll
      for (int j = 0; j < 8; ++j) b[j] = Bs[kk][tx * 8 + j];
#pragma unroll
      for (int i = 0; i < 4; ++i)
#pragma unroll
        for (int j = 0; j < 8; ++j) acc[i][j] = fmaf(a[i], b[j], acc[i][j]);
    }
    __syncthreads();
  }

#pragma unroll
  for (int i = 0; i < 4; ++i) {
    unsigned int* cp = C + (size_t)(rowBase + ty * 4 + i) * 64 + tx * 4;
    uint4 v;
    v.x = pack_bf2(acc[i][0], acc[i][1]);
    v.y = pack_bf2(acc[i][2], acc[i][3]);
    v.z = pack_bf2(acc[i][4], acc[i][5]);
    v.w = pack_bf2(acc[i][6], acc[i][7]);
    *(uint4*)cp = v;
  }
}

// ---------------------------------------------------------------------------
// bf16-input GEMM (A = packed bf16 pairs, nontemporal read), bf16 output.
// ---------------------------------------------------------------------------
__global__ __launch_bounds__(256) void gemm_bf16_kernel(
    const unsigned int* __restrict__ A, const float* __restrict__ W,
    unsigned int* __restrict__ C) {
  __shared__ float As[8][65];
  __shared__ float Bs[8][128];
  int t = threadIdx.x;
  int tx = t & 15;
  int ty = t >> 4;
  int rowBase = blockIdx.x * 64;

  float acc[4][8];
#pragma unroll
  for (int i = 0; i < 4; ++i)
#pragma unroll
    for (int j = 0; j < 8; ++j) acc[i][j] = 0.0f;

  int arow = t >> 2;          // 0..63
  int akk = (t & 3) * 2;      // 0,2,4,6
  int bkk = t >> 5;           // 0..7
  int bcol = (t & 31) * 4;    // 0..124

  const unsigned int* Aptr = A + (size_t)(rowBase + arow) * 64 + (akk >> 1);

  for (int kb = 0; kb < 128; kb += 8) {
    unsigned int av = __builtin_nontemporal_load(Aptr + (kb >> 1));
    float4 bv = *(const float4*)(W + (kb + bkk) * 128 + bcol);
    As[akk][arow] = __uint_as_float(av << 16);
    As[akk + 1][arow] = __uint_as_float(av & 0xffff0000u);
    *(float4*)&Bs[bkk][bcol] = bv;
    __syncthreads();
#pragma unroll
    for (int kk = 0; kk < 8; ++kk) {
      float a[4], b[8];
#pragma unroll
      for (int i = 0; i < 4; ++i) a[i] = As[kk][ty * 4 + i];
#pragma unroll
      for (int j = 0; j < 8; ++j) b[j] = Bs[kk][tx * 8 + j];
#pragma unroll
      for (int i = 0; i < 4; ++i)
#pragma unroll
        for (int j = 0; j < 8; ++j) acc[i][j] = fmaf(a[i], b[j], acc[i][j]);
    }
    __syncthreads();
  }

#pragma unroll
  for (int i = 0; i < 4; ++i) {
    unsigned int* cp = C + (size_t)(rowBase + ty * 4 + i) * 64 + tx * 4;
    uint4 v;
    v.x = pack_bf2(acc[i][0], acc[i][1]);
    v.y = pack_bf2(acc[i][2], acc[i][3]);
    v.z = pack_bf2(acc[i][4], acc[i][5]);
    v.w = pack_bf2(acc[i][6], acc[i][7]);
    *(uint4*)cp = v;
  }
}

// ---------------------------------------------------------------------------
// Aggregation over bf16 h. One wave per node; lane owns channels 2l,2l+1.
// BRANCHLESS exact-count: readlane index clamped to ecnt-1 (wave-uniform ->
// stays on SGPR path, single 16-load clause, no s_cbranch); padding iters
// re-load the SAME line as the last real edge (L1-hit, no new line request)
// with nm forced to 0 via select. This removes ~30% junk line traffic that
// round-8 padding paid, without round-9's clause-breaking guards.
// pool==0: write bf16 packed, nontemporal. pool==1: atomicAdd per-graph sums.
// ---------------------------------------------------------------------------
__global__ __launch_bounds__(256, 8) void agg_relu_kernel(
    const unsigned int* __restrict__ h, const int* __restrict__ cnt,
    const unsigned int* __restrict__ bucket2,
    const float* __restrict__ dinv, const float* __restrict__ bias,
    unsigned int* __restrict__ outb, const int* __restrict__ batch,
    float* __restrict__ sums, int pool) {
  int wave = threadIdx.x >> 6;
  int lane = threadIdx.x & 63;
  int n = blockIdx.x * 4 + wave;

  unsigned int ev =
      __builtin_nontemporal_load(&bucket2[(size_t)n * CAP + lane]);
  int ecnt = min(cnt[n], CAP);
  float di = dinv[n];

  float accx = 0.0f, accy = 0.0f;
  int em1 = ecnt - 1;
  for (int eb = 0; eb < ecnt; eb += 16) {
    unsigned int hv[16];
    float nmv[16];
#pragma unroll
    for (int i = 0; i < 16; ++i) {
      int e = eb + i;
      int ec = min(e, em1);                           // wave-uniform clamp
      unsigned int edge = __builtin_amdgcn_readlane(ev, ec);
      float nm = __uint_as_float(edge & 0xffff0000u) * di;
      nmv[i] = (e < ecnt) ? nm : 0.0f;                // branchless select
      hv[i] = h[(size_t)(edge & 0xffffu) * 64 + lane];
    }
#pragma unroll
    for (int i = 0; i < 16; ++i) {
      accx = fmaf(__uint_as_float(hv[i] << 16), nmv[i], accx);
      accy = fmaf(__uint_as_float(hv[i] & 0xffff0000u), nmv[i], accy);
    }
  }

  float sl = di * di;
  unsigned int hsv = h[(size_t)n * 64 + lane];
  float hsx = __uint_as_float(hsv << 16);
  float hsy = __uint_as_float(hsv & 0xffff0000u);
  float2 bv = ((const float2*)bias)[lane];
  float vx = fmaxf(fmaf(sl, hsx, accx) + bv.x, 0.0f);
  float vy = fmaxf(fmaf(sl, hsy, accy) + bv.y, 0.0f);

  if (!pool) {
    unsigned int o = pack_bf2(vx, vy);
    __builtin_nontemporal_store(o, &outb[(size_t)n * 64 + lane]);
  } else {
    int g = batch[n];
    atomicAdd(&sums[g * 128 + 2 * lane], vx);
    atomicAdd(&sums[g * 128 + 2 * lane + 1], vy);
  }
}

// ---------------------------------------------------------------------------
// Head: per-graph count via binary search on sorted batch (folded in),
// g = sums/cnt; out = normalize(g @ Wl + bl). 1 wave per graph.
// ---------------------------------------------------------------------------
__global__ __launch_bounds__(64) void head_kernel(
    const int* __restrict__ batch, const float* __restrict__ sums,
    const float* __restrict__ Wl, const float* __restrict__ bl,
    float* __restrict__ out) {
  int g = blockIdx.x;
  int j = threadIdx.x;
  __shared__ float gv[128];
  __shared__ int bnd[2];
  if (j < 2) {
    int v = g + j;
    int lo = 0, hi = N_NODES;
    while (lo < hi) {
      int m = (lo + hi) >> 1;
      if (batch[m] < v) lo = m + 1; else hi = m;
    }
    bnd[j] = lo;
  }
  __syncthreads();
  float c = fmaxf((float)(bnd[1] - bnd[0]), 1.0f);
  float inv = 1.0f / c;
  gv[j] = sums[g * 128 + j] * inv;
  gv[j + 64] = sums[g * 128 + 64 + j] * inv;
  __syncthreads();
  float acc = bl[j];
#pragma unroll 8
  for (int k = 0; k < 128; ++k) acc = fmaf(gv[k], Wl[k * 64 + j], acc);
  float ss = acc * acc;
#pragma unroll
  for (int d = 32; d > 0; d >>= 1) ss += __shfl_xor(ss, d);
  float nrm = sqrtf(ss);
  out[g * 64 + j] = acc / fmaxf(nrm, 1e-12f);
}

// ---------------------------------------------------------------------------
extern "C" void kernel_launch(void* const* d_in, const int* in_sizes, int n_in,
                              void* d_out, int out_size, void* d_ws, size_t ws_size,
                              hipStream_t stream) {
  const float* x  = (const float*)d_in[0];
  const float* W1 = (const float*)d_in[1];
  const float* b1 = (const float*)d_in[2];
  const float* W2 = (const float*)d_in[3];
  const float* b2 = (const float*)d_in[4];
  const float* Wl = (const float*)d_in[5];
  const float* bl = (const float*)d_in[6];
  const int* edge_index = (const int*)d_in[7];   // [2, E] int32
  const int* batch = (const int*)d_in[8];
  float* out = (float*)d_out;

  const int* esrc_in = edge_index;
  const int* edst_in = edge_index + N_EDGES;

  // workspace carve-up (~36.2 MB)
  char* p = (char*)d_ws;
  unsigned int* bufA = (unsigned int*)p;                      // bf16 h (pairs)
  p += (size_t)N_NODES * 64 * 4;                              // 10.24 MB
  unsigned int* bufB = (unsigned int*)p;                      // bf16 relu out
  p += (size_t)N_NODES * 64 * 4;                              // 10.24 MB
  int* cnt    = (int*)p;    p += (size_t)N_NODES * 4;         // 160 KB
  float* sums = (float*)p;  p += (size_t)N_GRAPHS * 128 * 4;  // 32 KB
  float* dinv = (float*)p;  p += (size_t)N_NODES * 4;         // 160 KB
  unsigned short* bucket = (unsigned short*)p;
  p += (size_t)N_NODES * CAP * 2;                              // 5.12 MB
  unsigned int* bucket2 = (unsigned int*)p;
  p += (size_t)N_NODES * CAP * 4;                              // 10.24 MB

  // zero cnt + sums in one contiguous memset (adjacent)
  hipMemsetAsync(cnt, 0, (size_t)N_NODES * 4 + (size_t)N_GRAPHS * 128 * 4,
                 stream);

  int ceilN = (N_NODES + 255) / 256;   // 157
  int ceilE = (N_EDGES + 255) / 256;   // 2500

  scatter_bucket_kernel<<<ceilE, 256, 0, stream>>>(esrc_in, edst_in, cnt, bucket);
  dinv_kernel<<<ceilN, 256, 0, stream>>>(cnt, dinv);
  finalize_kernel<<<N_NODES / 4, 256, 0, stream>>>(cnt, bucket, dinv, bucket2);

  // layer 1: h = bf16(x @ W1) ; agg+bias+relu -> bufB (bf16, nontemporal)
  gemm_f32_kernel<<<N_NODES / 64, 256, 0, stream>>>(x, W1, bufA);
  agg_relu_kernel<<<N_NODES / 4, 256, 0, stream>>>(
      bufA, cnt, bucket2, dinv, b1, bufB, batch, sums, 0);

  // layer 2: h = bf16(bufB @ W2) ; agg+bias+relu fused with mean-pool accum
  gemm_bf16_kernel<<<N_NODES / 64, 256, 0, stream>>>(bufB, W2, bufA);
  agg_relu_kernel<<<N_NODES / 4, 256, 0, stream>>>(
      bufA, cnt, bucket2, dinv, b2, nullptr, batch, sums, 1);

  // head: count via binary search, mean, linear, L2 normalize
  head_kernel<<<N_GRAPHS, 64, 0, stream>>>(batch, sums, Wl, bl, out);
}

// Round 15
// 300.196 us; speedup vs baseline: 1.1652x; 1.0716x over previous
//
#include <hip/hip_runtime.h>
#include <hip/hip_bf16.h>

#define N_NODES 40000
#define N_EDGES 640000
#define IN_DIM 128
#define HIDDEN 128
#define OUT_DIM 64
#define N_GRAPHS 64
#define CAP 64   // bucket capacity per node (Poisson(16); P(max>=64) ~ 4e-15)

typedef short bf16x8 __attribute__((ext_vector_type(8)));
typedef float f32x4 __attribute__((ext_vector_type(4)));

// RNE round fp32->bf16 helpers
__device__ inline unsigned short bf16_1(float a) {
  unsigned int ua = __float_as_uint(a);
  ua = ua + 0x7fffu + ((ua >> 16) & 1u);
  return (unsigned short)(ua >> 16);
}
__device__ inline unsigned int pack_bf2(float a, float b) {
  unsigned int ua = __float_as_uint(a);
  ua = ua + 0x7fffu + ((ua >> 16) & 1u);
  unsigned int ub = __float_as_uint(b);
  ub = ub + 0x7fffu + ((ub >> 16) & 1u);
  return (ua >> 16) | (ub & 0xffff0000u);
}

// ---------------------------------------------------------------------------
// Single-pass bucket scatter: cnt[d]++ and record src in d's bucket (ushort).
// ---------------------------------------------------------------------------
__global__ __launch_bounds__(256) void scatter_bucket_kernel(
    const int* __restrict__ src, const int* __restrict__ dst,
    int* __restrict__ cnt, unsigned short* __restrict__ bucket) {
  int e = blockIdx.x * 256 + threadIdx.x;
  if (e >= N_EDGES) return;
  int d = dst[e];
  int s = src[e];
  int p = atomicAdd(&cnt[d], 1);
  if (p < CAP) bucket[(size_t)d * CAP + p] = (unsigned short)s;
}

// ---------------------------------------------------------------------------
// Finalize: one wave per node. Re-pack bucket entry -> uint:
//   (bf16(rsqrt(cnt[src]+1)) << 16) | src      (dinv computed inline)
// ---------------------------------------------------------------------------
__global__ __launch_bounds__(256) void finalize_kernel(
    const int* __restrict__ cnt, const unsigned short* __restrict__ bucket,
    unsigned int* __restrict__ bucket2) {
  int wave = threadIdx.x >> 6;
  int lane = threadIdx.x & 63;
  int n = blockIdx.x * 4 + wave;
  int ecnt = min(cnt[n], CAP);
  unsigned int v = 0;
  if (lane < ecnt) {
    int s = bucket[(size_t)n * CAP + lane];
    float dv = rsqrtf((float)cnt[s] + 1.0f);
    unsigned int d = __float_as_uint(dv);
    d = d + 0x7fffu + ((d >> 16) & 1u);          // RNE to bf16
    v = (d & 0xffff0000u) | (unsigned int)s;
  }
  bucket2[(size_t)n * CAP + lane] = v;
}

// ---------------------------------------------------------------------------
// W prep: Wt[n][k] = bf16(W[k][n])  (128x128, transposed for MFMA B-frags)
// ---------------------------------------------------------------------------
__global__ __launch_bounds__(256) void wprep_kernel(
    const float* __restrict__ W, unsigned short* __restrict__ Wt) {
  int idx = blockIdx.x * 256 + threadIdx.x;   // 64 blocks x 256 = 16384
  int k = idx >> 7;
  int n = idx & 127;
  Wt[n * 128 + k] = bf16_1(W[k * 128 + n]);
}

// ---------------------------------------------------------------------------
// fp32-input GEMM, bf16 output: C[M,128] = A[M,128] @ W[128,128]. (layer 1)
// ---------------------------------------------------------------------------
__global__ __launch_bounds__(256) void gemm_f32_kernel(
    const float* __restrict__ A, const float* __restrict__ W,
    unsigned int* __restrict__ C) {  // C: bf16 pairs, row stride 64 uints
  __shared__ float As[8][65];
  __shared__ float Bs[8][128];
  int t = threadIdx.x;
  int tx = t & 15;
  int ty = t >> 4;
  int rowBase = blockIdx.x * 64;

  float acc[4][8];
#pragma unroll
  for (int i = 0; i < 4; ++i)
#pragma unroll
    for (int j = 0; j < 8; ++j) acc[i][j] = 0.0f;

  int arow = t >> 2;          // 0..63
  int akk = (t & 3) * 2;      // 0,2,4,6
  int bkk = t >> 5;           // 0..7
  int bcol = (t & 31) * 4;    // 0..124

  const float* Aptr = A + (size_t)(rowBase + arow) * 128 + akk;

  for (int kb = 0; kb < 128; kb += 8) {
    float2 av = *(const float2*)(Aptr + kb);
    float4 bv = *(const float4*)(W + (kb + bkk) * 128 + bcol);
    As[akk][arow] = av.x;
    As[akk + 1][arow] = av.y;
    *(float4*)&Bs[bkk][bcol] = bv;
    __syncthreads();
#pragma unroll
    for (int kk = 0; kk < 8; ++kk) {
      float a[4], b[8];
#pragma unroll
      for (int i = 0; i < 4; ++i) a[i] = As[kk][ty * 4 + i];
#pragma unroll
      for (int j = 0; j < 8; ++j) b[j] = Bs[kk][tx * 8 + j];
#pragma unroll
      for (int i = 0; i < 4; ++i)
#pragma unroll
        for (int j = 0; j < 8; ++j) acc[i][j] = fmaf(a[i], b[j], acc[i][j]);
    }
    __syncthreads();
  }

#pragma unroll
  for (int i = 0; i < 4; ++i) {
    unsigned int* cp = C + (size_t)(rowBase + ty * 4 + i) * 64 + tx * 4;
    uint4 v;
    v.x = pack_bf2(acc[i][0], acc[i][1]);
    v.y = pack_bf2(acc[i][2], acc[i][3]);
    v.z = pack_bf2(acc[i][4], acc[i][5]);
    v.w = pack_bf2(acc[i][6], acc[i][7]);
    *(uint4*)cp = v;
  }
}

// ---------------------------------------------------------------------------
// MFMA GEMM (layer 2): C[M,128] = A[M,128] @ W, A bf16-packed, Wt bf16 [n][k].
// 256 thr = 4 waves; wave owns 16 rows x 128 cols = 8 tiles x 4 K-steps of
// mfma_f32_16x16x32_bf16. Frag layouts (lane l, elem j):
//   A[l&15][kb*32 + (l>>4)*8 + j]   B: Wt[nt*16 + (l&15)][kb*32 + (l>>4)*8+j]
//   D: row (l>>4)*4+r, col l&15  (verified C/D mapping)
// No LDS, no barriers; A/Wt reads form 64B segments, Wt (32KB) is L1-hot.
// ---------------------------------------------------------------------------
__global__ __launch_bounds__(256) void gemm_mfma_kernel(
    const unsigned int* __restrict__ A, const unsigned short* __restrict__ Wt,
    unsigned int* __restrict__ C) {
  int wave = threadIdx.x >> 6;
  int lane = threadIdx.x & 63;
  int rowBase = blockIdx.x * 64 + wave * 16;
  int lr = lane & 15;
  int lg = lane >> 4;

  // A fragments for the wave's 16 rows, all 4 K-steps
  bf16x8 afrag[4];
  const unsigned int* arow = A + (size_t)(rowBase + lr) * 64;
#pragma unroll
  for (int kb = 0; kb < 4; ++kb) {
    uint4 av = *(const uint4*)(arow + kb * 16 + lg * 4);
    afrag[kb] = *reinterpret_cast<const bf16x8*>(&av);
  }

  f32x4 acc[8];
#pragma unroll
  for (int nt = 0; nt < 8; ++nt) acc[nt] = (f32x4){0.f, 0.f, 0.f, 0.f};

#pragma unroll
  for (int nt = 0; nt < 8; ++nt) {
    const unsigned short* wrow = Wt + (size_t)(nt * 16 + lr) * 128;
#pragma unroll
    for (int kb = 0; kb < 4; ++kb) {
      bf16x8 bfrag = *reinterpret_cast<const bf16x8*>(wrow + kb * 32 + lg * 8);
      acc[nt] = __builtin_amdgcn_mfma_f32_16x16x32_bf16(afrag[kb], bfrag,
                                                        acc[nt], 0, 0, 0);
    }
  }

  unsigned short* Cs = (unsigned short*)C;
#pragma unroll
  for (int nt = 0; nt < 8; ++nt) {
#pragma unroll
    for (int r = 0; r < 4; ++r) {
      int row = rowBase + lg * 4 + r;
      int col = nt * 16 + lr;
      Cs[(size_t)row * 128 + col] = bf16_1(acc[nt][r]);
    }
  }
}

// ---------------------------------------------------------------------------
// Aggregation over bf16 h (round-8 config: padded unconditional unroll-16).
// One wave per node; lane owns channels 2l,2l+1. Wave-uniform readlane decode
// (SGPR path). Junk iters (slot empty) load row 0 with nm=0, L1-hot = free.
// di computed from cnt[n] (dinv array eliminated).
// pool==0: write bf16 packed, nontemporal. pool==1: atomicAdd per-graph sums.
// ---------------------------------------------------------------------------
__global__ __launch_bounds__(256) void agg_relu_kernel(
    const unsigned int* __restrict__ h, const int* __restrict__ cnt,
    const unsigned int* __restrict__ bucket2, const float* __restrict__ bias,
    unsigned int* __restrict__ outb, const int* __restrict__ batch,
    float* __restrict__ sums, int pool) {
  int wave = threadIdx.x >> 6;
  int lane = threadIdx.x & 63;
  int n = blockIdx.x * 4 + wave;

  unsigned int ev =
      __builtin_nontemporal_load(&bucket2[(size_t)n * CAP + lane]);
  int rawc = cnt[n];
  int ecnt = min(rawc, CAP);
  float di = rsqrtf((float)rawc + 1.0f);

  float accx = 0.0f, accy = 0.0f;
  int iters = (ecnt + 15) & ~15;   // pad to multiple of 16 (16..64)
  for (int eb = 0; eb < iters; eb += 16) {
#pragma unroll
    for (int i = 0; i < 16; ++i) {
      int e = eb + i;                                   // wave-uniform
      unsigned int edge = __builtin_amdgcn_readlane(ev, e);
      int s = (int)(edge & 0xffffu);
      float nm = __uint_as_float(edge & 0xffff0000u) * di;
      unsigned int hv = h[(size_t)s * 64 + lane];
      accx = fmaf(__uint_as_float(hv << 16), nm, accx);
      accy = fmaf(__uint_as_float(hv & 0xffff0000u), nm, accy);
    }
  }

  float sl = di * di;
  unsigned int hsv = h[(size_t)n * 64 + lane];
  float hsx = __uint_as_float(hsv << 16);
  float hsy = __uint_as_float(hsv & 0xffff0000u);
  float2 bv = ((const float2*)bias)[lane];
  float vx = fmaxf(fmaf(sl, hsx, accx) + bv.x, 0.0f);
  float vy = fmaxf(fmaf(sl, hsy, accy) + bv.y, 0.0f);

  if (!pool) {
    unsigned int o = pack_bf2(vx, vy);
    __builtin_nontemporal_store(o, &outb[(size_t)n * 64 + lane]);
  } else {
    int g = batch[n];
    atomicAdd(&sums[g * 128 + 2 * lane], vx);
    atomicAdd(&sums[g * 128 + 2 * lane + 1], vy);
  }
}

// ---------------------------------------------------------------------------
// Head: per-graph count via binary search on sorted batch (folded in),
// g = sums/cnt; out = normalize(g @ Wl + bl). 1 wave per graph.
// ---------------------------------------------------------------------------
__global__ __launch_bounds__(64) void head_kernel(
    const int* __restrict__ batch, const float* __restrict__ sums,
    const float* __restrict__ Wl, const float* __restrict__ bl,
    float* __restrict__ out) {
  int g = blockIdx.x;
  int j = threadIdx.x;
  __shared__ float gv[128];
  __shared__ int bnd[2];
  if (j < 2) {
    int v = g + j;
    int lo = 0, hi = N_NODES;
    while (lo < hi) {
      int m = (lo + hi) >> 1;
      if (batch[m] < v) lo = m + 1; else hi = m;
    }
    bnd[j] = lo;
  }
  __syncthreads();
  float c = fmaxf((float)(bnd[1] - bnd[0]), 1.0f);
  float inv = 1.0f / c;
  gv[j] = sums[g * 128 + j] * inv;
  gv[j + 64] = sums[g * 128 + 64 + j] * inv;
  __syncthreads();
  float acc = bl[j];
#pragma unroll 8
  for (int k = 0; k < 128; ++k) acc = fmaf(gv[k], Wl[k * 64 + j], acc);
  float ss = acc * acc;
#pragma unroll
  for (int d = 32; d > 0; d >>= 1) ss += __shfl_xor(ss, d);
  float nrm = sqrtf(ss);
  out[g * 64 + j] = acc / fmaxf(nrm, 1e-12f);
}

// ---------------------------------------------------------------------------
extern "C" void kernel_launch(void* const* d_in, const int* in_sizes, int n_in,
                              void* d_out, int out_size, void* d_ws, size_t ws_size,
                              hipStream_t stream) {
  const float* x  = (const float*)d_in[0];
  const float* W1 = (const float*)d_in[1];
  const float* b1 = (const float*)d_in[2];
  const float* W2 = (const float*)d_in[3];
  const float* b2 = (const float*)d_in[4];
  const float* Wl = (const float*)d_in[5];
  const float* bl = (const float*)d_in[6];
  const int* edge_index = (const int*)d_in[7];   // [2, E] int32
  const int* batch = (const int*)d_in[8];
  float* out = (float*)d_out;

  const int* esrc_in = edge_index;
  const int* edst_in = edge_index + N_EDGES;

  // workspace carve-up (~36.1 MB)
  char* p = (char*)d_ws;
  unsigned int* bufA = (unsigned int*)p;                      // bf16 h (pairs)
  p += (size_t)N_NODES * 64 * 4;                              // 10.24 MB
  unsigned int* bufB = (unsigned int*)p;                      // bf16 relu out
  p += (size_t)N_NODES * 64 * 4;                              // 10.24 MB
  int* cnt    = (int*)p;    p += (size_t)N_NODES * 4;         // 160 KB
  float* sums = (float*)p;  p += (size_t)N_GRAPHS * 128 * 4;  // 32 KB
  unsigned short* bucket = (unsigned short*)p;
  p += (size_t)N_NODES * CAP * 2;                              // 5.12 MB
  unsigned int* bucket2 = (unsigned int*)p;
  p += (size_t)N_NODES * CAP * 4;                              // 10.24 MB
  unsigned short* Wt2 = (unsigned short*)p;
  p += 128 * 128 * 2;                                          // 32 KB

  // zero cnt + sums in one contiguous memset (adjacent)
  hipMemsetAsync(cnt, 0, (size_t)N_NODES * 4 + (size_t)N_GRAPHS * 128 * 4,
                 stream);

  int ceilE = (N_EDGES + 255) / 256;   // 2500

  scatter_bucket_kernel<<<ceilE, 256, 0, stream>>>(esrc_in, edst_in, cnt, bucket);
  wprep_kernel<<<64, 256, 0, stream>>>(W2, Wt2);
  finalize_kernel<<<N_NODES / 4, 256, 0, stream>>>(cnt, bucket, bucket2);

  // layer 1: h = bf16(x @ W1) ; agg+bias+relu -> bufB (bf16, nontemporal)
  gemm_f32_kernel<<<N_NODES / 64, 256, 0, stream>>>(x, W1, bufA);
  agg_relu_kernel<<<N_NODES / 4, 256, 0, stream>>>(
      bufA, cnt, bucket2, b1, bufB, batch, sums, 0);

  // layer 2: h = bf16(bufB @ W2) via MFMA ; agg fused with mean-pool accum
  gemm_mfma_kernel<<<N_NODES / 64, 256, 0, stream>>>(bufB, Wt2, bufA);
  agg_relu_kernel<<<N_NODES / 4, 256, 0, stream>>>(
      bufA, cnt, bucket2, b2, nullptr, batch, sums, 1);

  // head: count via binary search, mean, linear, L2 normalize
  head_kernel<<<N_GRAPHS, 64, 0, stream>>>(batch, sums, Wl, bl, out);
}